// Round 13
// baseline (221.170 us; speedup 1.0000x reference)
//
#include <hip/hip_runtime.h>
#include <hip/hip_fp16.h>

typedef _Float16 half_t;
typedef __attribute__((ext_vector_type(2))) _Float16 f16x2;
typedef __attribute__((ext_vector_type(8))) _Float16 f16x8;
typedef __attribute__((ext_vector_type(4))) float f32x4;

// ---------------------------------------------------------------------------
// Separable MLP: h = relu(z[src].W1a + z[dst].W1b + b1) ; out = h.W2 + b2
// Phase 0 (prep): blocks [0,128): W1 -> f16 B-fragment blob (64 KB);
//   blocks [128,..): z fp32 -> zh f16 (separate prep beats fused cvt: R12's
//   in-gemm cvt re-spilled ~44 MB of writes).
// Phase 1 (gemm_uv): Y[node] = [zh@W1a | zh@W1b], M=16/wave, BLOCK=512:
//   64 KB LDS x 2 blocks/CU now carries 16 waves/CU (R10's 256-thr block had
//   only 8 -> 17% occupancy, A-latency exposed). No software A-prefetch --
//   waves run 1-2 iterations; TLP does the hiding; keeps regs ~100 < 128 cap.
// Phase 2 (edge_decode): out[e] = b2 + relu(Y[s][0:128]+Y[d][128:256]+b1).W2
//   16 lanes/edge, 2048 blocks, 2-deep pipeline (R10: 73 us, fabric-bound).
// Y column permute: position j in each 128-half holds hidden index
//   n(j) = (j&7)*16 + (j>>3); b1/W2 permuted identically in phase 2.
// ---------------------------------------------------------------------------

// B-fragment (ks in 0..3, nt in 0..15): lane L elem j holds
//   B[k = ks*32 + (L>>4)*8 + j][ncol = nt*16 + (L&15)]
// where B[k][ncol] = W1[(ncol<128 ? k : 128+k)][ncol & 127].
// Flat f16 index t = ((ks*16 + nt)*64 + L)*8 + j.
__global__ void prep_kernel(const float* __restrict__ z,
                            const float* __restrict__ W1,
                            half_t* __restrict__ zh,
                            half_t* __restrict__ w1s, int n8) {
    if (blockIdx.x < 128) {
        const int t = blockIdx.x * 256 + threadIdx.x;   // 0..32767
        const int j  = t & 7;
        const int L  = (t >> 3) & 63;
        const int nt = (t >> 9) & 15;
        const int ks = t >> 13;
        const int k    = ks * 32 + (L >> 4) * 8 + j;
        const int ncol = nt * 16 + (L & 15);
        const int row  = (ncol < 128) ? k : 128 + k;
        w1s[t] = (half_t)W1[row * 128 + (ncol & 127)];
    } else {
        const int t = (blockIdx.x - 128) * 256 + threadIdx.x;
        if (t < n8) {
            const float4 a = reinterpret_cast<const float4*>(z)[2 * t];
            const float4 b = reinterpret_cast<const float4*>(z)[2 * t + 1];
            f16x8 o;
            o[0] = (_Float16)a.x; o[1] = (_Float16)a.y;
            o[2] = (_Float16)a.z; o[3] = (_Float16)a.w;
            o[4] = (_Float16)b.x; o[5] = (_Float16)b.y;
            o[6] = (_Float16)b.z; o[7] = (_Float16)b.w;
            reinterpret_cast<f16x8*>(zh)[t] = o;
        }
    }
}

__global__ __launch_bounds__(512, 2)
void gemm_uv_kernel(const half_t* __restrict__ zh,
                    const half_t* __restrict__ w1s,
                    half_t* __restrict__ Y,
                    int n_groups, int stride_groups) {
    __shared__ __align__(16) half_t w1_lds[32768];   // 64 KB
    const int wave = threadIdx.x >> 6;               // 0..7
    const int lane = threadIdx.x & 63;

    // Stage 64 KB via global_load_lds: 8 rounds x 8 waves x 1024 B.
    // LDS dest = uniform base + lane*16 = flat fragment layout (R7 verified
    // conflict-free).
#pragma unroll
    for (int rnd = 0; rnd < 8; ++rnd) {
        const int chunk = rnd * 8 + wave;       // 0..63, wave-uniform
        const char* gp = (const char*)w1s + chunk * 1024 + lane * 16;
        __builtin_amdgcn_global_load_lds(
            (const __attribute__((address_space(1))) void*)gp,
            (__attribute__((address_space(3))) void*)
                ((char*)w1_lds + chunk * 1024),
            16, 0, 0);
    }
    __syncthreads();

    const int nlo  = lane & 15;
    const int quad = lane >> 4;
    const f16x8* blds = reinterpret_cast<const f16x8*>(w1_lds);

    // N_NODES = 16 * n_groups exactly -> no bounds guards anywhere.
    for (int g = blockIdx.x * 8 + wave; g < n_groups; g += stride_groups) {
        const half_t* arow = zh + ((size_t)(g * 16 + nlo) * 128) + quad * 8;
        f16x8 av[4];
#pragma unroll
        for (int ks = 0; ks < 4; ++ks)
            av[ks] = *reinterpret_cast<const f16x8*>(arow + ks * 32);

        f32x4 acc[16];
#pragma unroll
        for (int nt = 0; nt < 16; ++nt) acc[nt] = (f32x4){0.f, 0.f, 0.f, 0.f};

#pragma unroll
        for (int ks = 0; ks < 4; ++ks) {
            const f16x8* bp = blds + ks * 1024 + lane;
#pragma unroll
            for (int nt = 0; nt < 16; ++nt)
                acc[nt] = __builtin_amdgcn_mfma_f32_16x16x32_f16(
                    av[ks], bp[nt * 64], acc[nt], 0, 0, 0);
        }

        // C/D: row m = quad*4 + r, col = nt*16 + nlo.
#pragma unroll
        for (int r = 0; r < 4; ++r) {
            const int nr = g * 16 + quad * 4 + r;
            f16x8 up, vp;
#pragma unroll
            for (int t = 0; t < 8; ++t) {
                up[t] = (_Float16)acc[t][r];
                vp[t] = (_Float16)acc[8 + t][r];
            }
            *reinterpret_cast<f16x8*>(Y + (size_t)nr * 256 + nlo * 8) = up;
            *reinterpret_cast<f16x8*>(Y + (size_t)nr * 256 + 128 + nlo * 8) = vp;
        }
    }
}

static __device__ __forceinline__ f16x2 pair2(const f16x8& v, int p) {
    f16x2 r; r[0] = v[2 * p]; r[1] = v[2 * p + 1]; return r;
}

// Edge phase: 16 lanes per edge (4 edges/wave/iter), coalesced 256-B segment
// gathers. Two-deep pipeline: indices fetched 2 iters ahead, u/v 1 iter ahead.
__global__ __launch_bounds__(256, 8)
void edge_decode_kernel(const half_t* __restrict__ Y,
                        const int* __restrict__ eidx,
                        const float* __restrict__ b1,
                        const float* __restrict__ W2,
                        const float* __restrict__ b2,
                        float* __restrict__ out,
                        int n_edges, int stride_e) {
    __shared__ __align__(16) half_t b1h[128];
    __shared__ __align__(16) half_t w2h[128];
    if (threadIdx.x < 128) {
        const int i = threadIdx.x;
        const int n = (i & 7) * 16 + (i >> 3);   // match Y's column permute
        b1h[i] = (half_t)b1[n];
        w2h[i] = (half_t)W2[n];
    }
    __syncthreads();

    const int lane  = threadIdx.x & 63;
    const int sl    = lane & 15;    // 16-B slice within the 256-B half-row
    const int eslot = lane >> 4;    // which of the wave's 4 edges
    const f16x8 bv = reinterpret_cast<const f16x8*>(b1h)[sl];
    const f16x8 wv = reinterpret_cast<const f16x8*>(w2h)[sl];
    const float b2v = b2[0];
    const f16x2 zero2 = {(_Float16)0, (_Float16)0};

    const int w = blockIdx.x * 4 + (threadIdx.x >> 6);
    int e0 = w * 4;
    if (e0 >= n_edges) return;

    int ec = e0 + eslot; if (ec >= n_edges) ec = 0;
    int s1 = eidx[ec];
    int d1 = eidx[n_edges + ec];
    f16x8 u0 = *reinterpret_cast<const f16x8*>(Y + (size_t)s1 * 256 + sl * 8);
    f16x8 v0 = *reinterpret_cast<const f16x8*>(Y + (size_t)d1 * 256 + 128 +
                                               sl * 8);
    {
        int en = e0 + stride_e + eslot;
        if (en >= n_edges) en = 0;
        s1 = eidx[en];
        d1 = eidx[n_edges + en];
    }

    for (; e0 < n_edges; e0 += stride_e) {
        const int e = e0 + eslot;
        const bool valid = (e < n_edges);

        const f16x8 u1 = *reinterpret_cast<const f16x8*>(
            Y + (size_t)s1 * 256 + sl * 8);
        const f16x8 v1 = *reinterpret_cast<const f16x8*>(
            Y + (size_t)d1 * 256 + 128 + sl * 8);

        {
            int en = e0 + 2 * stride_e + eslot;
            if (en >= n_edges) en = 0;
            s1 = eidx[en];
            d1 = eidx[n_edges + en];
        }

        float acc = 0.f;
#pragma unroll
        for (int p = 0; p < 4; ++p) {
            f16x2 h2 = pair2(u0, p) + pair2(v0, p) + pair2(bv, p);
            h2 = __builtin_elementwise_max(h2, zero2);
            acc = __builtin_amdgcn_fdot2(h2, pair2(wv, p), acc, false);
        }
        acc += __shfl_xor(acc, 1);
        acc += __shfl_xor(acc, 2);
        acc += __shfl_xor(acc, 4);
        acc += __shfl_xor(acc, 8);
        if (sl == 0 && valid) out[e] = acc + b2v;

        u0 = u1; v0 = v1;
    }
}

// Insurance fallback (only if workspace is unexpectedly tiny): correct, slow.
__global__ void naive_edge_kernel(const float* __restrict__ z,
                                  const int* __restrict__ eidx,
                                  const float* __restrict__ W1,
                                  const float* __restrict__ b1,
                                  const float* __restrict__ W2,
                                  const float* __restrict__ b2,
                                  float* __restrict__ out, int n_edges) {
    __shared__ float feat[256];
    __shared__ float red[2];
    const int e = blockIdx.x;
    const int t = threadIdx.x;           // 128 threads
    const int s = eidx[e], d = eidx[n_edges + e];
    feat[t] = z[(size_t)s * 128 + t];
    feat[128 + t] = z[(size_t)d * 128 + t];
    __syncthreads();
    float h = b1[t];
    for (int k = 0; k < 256; ++k) h = fmaf(feat[k], W1[k * 128 + t], h);
    float p = fmaxf(h, 0.f) * W2[t];
    for (int off = 32; off; off >>= 1) p += __shfl_down(p, off);
    if ((t & 63) == 0) red[t >> 6] = p;
    __syncthreads();
    if (t == 0) out[e] = red[0] + red[1] + b2[0];
}

extern "C" void kernel_launch(void* const* d_in, const int* in_sizes, int n_in,
                              void* d_out, int out_size, void* d_ws,
                              size_t ws_size, hipStream_t stream) {
    const float* z   = (const float*)d_in[0];
    const int* eidx  = (const int*)d_in[1];   // int64 ref passed as int32
    const float* W1  = (const float*)d_in[2];
    const float* b1  = (const float*)d_in[3];
    const float* W2  = (const float*)d_in[4];
    const float* b2  = (const float*)d_in[5];
    float* out       = (float*)d_out;

    const int nz      = in_sizes[0];          // 12,800,000
    const int n_nodes = nz / 128;             // 100,000
    const int n_edges = in_sizes[1] / 2;      // 1,000,000

    const size_t Y_bytes   = (size_t)n_nodes * 256 * sizeof(half_t); // 51.2 MB
    const size_t zh_bytes  = (size_t)nz * sizeof(half_t);            // 25.6 MB
    const size_t w1s_bytes = 32768 * sizeof(half_t);                 // 64 KB

    if (ws_size >= Y_bytes + zh_bytes + w1s_bytes) {
        half_t* Y   = (half_t*)d_ws;
        half_t* zh  = (half_t*)((char*)d_ws + Y_bytes);
        half_t* w1s = (half_t*)((char*)d_ws + Y_bytes + zh_bytes);

        const int n8 = nz / 8;                      // 1.6M f16x8 chunks
        const int zblocks = (n8 + 255) / 256;       // 6250
        prep_kernel<<<128 + zblocks, 256, 0, stream>>>(z, W1, zh, w1s, n8);

        const int n_groups = n_nodes / 16;          // 6250 exact
        const int gblocks  = 512;                   // 512-thr blocks, 2/CU
        gemm_uv_kernel<<<gblocks, 512, 0, stream>>>(zh, w1s, Y, n_groups,
                                                    gblocks * 8);

        const int eblocks = 2048;                   // 8 blocks/CU -> 32 w/CU
        edge_decode_kernel<<<eblocks, 256, 0, stream>>>(
            Y, eidx, b1, W2, b2, out, n_edges, eblocks * 4 * 4);
    } else {
        naive_edge_kernel<<<n_edges, 128, 0, stream>>>(z, eidx, W1, b1, W2, b2,
                                                       out, n_edges);
    }
}

// Round 14
// 211.979 us; speedup vs baseline: 1.0434x; 1.0434x over previous
//
#include <hip/hip_runtime.h>
#include <hip/hip_fp16.h>

typedef _Float16 half_t;
typedef __attribute__((ext_vector_type(2))) _Float16 f16x2;
typedef __attribute__((ext_vector_type(8))) _Float16 f16x8;
typedef __attribute__((ext_vector_type(4))) float f32x4;

// ---------------------------------------------------------------------------
// Separable MLP: h = relu(z[src].W1a + z[dst].W1b + b1) ; out = h.W2 + b2
// Structure = R10 (best measured: 213.5 us), + 3-deep edge pipeline.
// Phase 0 (prep): blocks [0,128): W1 -> f16 B-fragment blob (64 KB);
//   blocks [128,..): z fp32 -> zh f16. (Separate prep beats fused cvt:
//   R12's in-gemm cvt spilled ~44 MB. Separate beats skipping zh: R6-R8.)
// Phase 1 (gemm_uv): Y[node] = [zh@W1a | zh@W1b], 256-thr blocks, grid 512,
//   M=16/wave, A-prefetch 1 group ahead, W1 via global_load_lds.
//   (R11 U/V-split, R12 fused-cvt, R13 512-thr block all regressed vs this.)
// Phase 2 (edge_decode): out[e] = b2 + relu(Y[s][0:128]+Y[d][128:256]+b1).W2
//   16 lanes/edge, 2048 blocks (8/CU), 3-deep pipeline: gathers 2 iters
//   ahead, indices 3 ahead. Fabric-bound at ~239 MB HBM-miss / 73 us.
// Y column permute: position j in each 128-half holds hidden index
//   n(j) = (j&7)*16 + (j>>3); b1/W2 permuted identically in phase 2.
// ---------------------------------------------------------------------------

// B-fragment (ks in 0..3, nt in 0..15): lane L elem j holds
//   B[k = ks*32 + (L>>4)*8 + j][ncol = nt*16 + (L&15)]
// where B[k][ncol] = W1[(ncol<128 ? k : 128+k)][ncol & 127].
// Flat f16 index t = ((ks*16 + nt)*64 + L)*8 + j.
__global__ void prep_kernel(const float* __restrict__ z,
                            const float* __restrict__ W1,
                            half_t* __restrict__ zh,
                            half_t* __restrict__ w1s, int n8) {
    if (blockIdx.x < 128) {
        const int t = blockIdx.x * 256 + threadIdx.x;   // 0..32767
        const int j  = t & 7;
        const int L  = (t >> 3) & 63;
        const int nt = (t >> 9) & 15;
        const int ks = t >> 13;
        const int k    = ks * 32 + (L >> 4) * 8 + j;
        const int ncol = nt * 16 + (L & 15);
        const int row  = (ncol < 128) ? k : 128 + k;
        w1s[t] = (half_t)W1[row * 128 + (ncol & 127)];
    } else {
        const int t = (blockIdx.x - 128) * 256 + threadIdx.x;
        if (t < n8) {
            const float4 a = reinterpret_cast<const float4*>(z)[2 * t];
            const float4 b = reinterpret_cast<const float4*>(z)[2 * t + 1];
            f16x8 o;
            o[0] = (_Float16)a.x; o[1] = (_Float16)a.y;
            o[2] = (_Float16)a.z; o[3] = (_Float16)a.w;
            o[4] = (_Float16)b.x; o[5] = (_Float16)b.y;
            o[6] = (_Float16)b.z; o[7] = (_Float16)b.w;
            reinterpret_cast<f16x8*>(zh)[t] = o;
        }
    }
}

__global__ __launch_bounds__(256, 2)
void gemm_uv_kernel(const half_t* __restrict__ zh,
                    const half_t* __restrict__ w1s,
                    half_t* __restrict__ Y,
                    int n_groups, int stride_groups) {
    __shared__ __align__(16) half_t w1_lds[32768];   // 64 KB
    const int wave = threadIdx.x >> 6;
    const int lane = threadIdx.x & 63;

    // Stage 64 KB via global_load_lds: LDS dest = uniform base + lane*16,
    // exactly the flat fragment layout. Conflict-free (R7 verified).
#pragma unroll
    for (int rnd = 0; rnd < 16; ++rnd) {
        const int chunk = rnd * 4 + wave;       // 0..63, wave-uniform
        const char* gp = (const char*)w1s + chunk * 1024 + lane * 16;
        __builtin_amdgcn_global_load_lds(
            (const __attribute__((address_space(1))) void*)gp,
            (__attribute__((address_space(3))) void*)
                ((char*)w1_lds + chunk * 1024),
            16, 0, 0);
    }
    __syncthreads();

    const int nlo  = lane & 15;
    const int quad = lane >> 4;
    const f16x8* blds = reinterpret_cast<const f16x8*>(w1_lds);

    int g = blockIdx.x * 4 + wave;
    if (g >= n_groups) return;

    // N_NODES = 16 * n_groups exactly -> no bounds guards anywhere.
    const half_t* arow = zh + ((size_t)(g * 16 + nlo) * 128) + quad * 8;
    f16x8 av[4];
#pragma unroll
    for (int ks = 0; ks < 4; ++ks)
        av[ks] = *reinterpret_cast<const f16x8*>(arow + ks * 32);

    for (; g < n_groups; g += stride_groups) {
        const int gn = g + stride_groups;
        const int gpi = (gn < n_groups) ? gn : g;  // harmless re-read on last
        const half_t* arow_n = zh + ((size_t)(gpi * 16 + nlo) * 128) + quad * 8;
        f16x8 avn[4];
#pragma unroll
        for (int ks = 0; ks < 4; ++ks)
            avn[ks] = *reinterpret_cast<const f16x8*>(arow_n + ks * 32);

        f32x4 acc[16];
#pragma unroll
        for (int nt = 0; nt < 16; ++nt) acc[nt] = (f32x4){0.f, 0.f, 0.f, 0.f};

#pragma unroll
        for (int ks = 0; ks < 4; ++ks) {
            const f16x8* bp = blds + ks * 1024 + lane;
#pragma unroll
            for (int nt = 0; nt < 16; ++nt)
                acc[nt] = __builtin_amdgcn_mfma_f32_16x16x32_f16(
                    av[ks], bp[nt * 64], acc[nt], 0, 0, 0);
        }

        // C/D: row m = quad*4 + r, col = nt*16 + nlo.
#pragma unroll
        for (int r = 0; r < 4; ++r) {
            const int nr = g * 16 + quad * 4 + r;
            f16x8 up, vp;
#pragma unroll
            for (int t = 0; t < 8; ++t) {
                up[t] = (_Float16)acc[t][r];
                vp[t] = (_Float16)acc[8 + t][r];
            }
            *reinterpret_cast<f16x8*>(Y + (size_t)nr * 256 + nlo * 8) = up;
            *reinterpret_cast<f16x8*>(Y + (size_t)nr * 256 + 128 + nlo * 8) = vp;
        }

#pragma unroll
        for (int ks = 0; ks < 4; ++ks) av[ks] = avn[ks];
    }
}

static __device__ __forceinline__ f16x2 pair2(const f16x8& v, int p) {
    f16x2 r; r[0] = v[2 * p]; r[1] = v[2 * p + 1]; return r;
}

// Edge phase: 16 lanes per edge (4 edges/wave/iter), coalesced 256-B segment
// gathers. Three-deep pipeline: gathers issued 2 iters ahead, indices 3.
__global__ __launch_bounds__(256, 8)
void edge_decode_kernel(const half_t* __restrict__ Y,
                        const int* __restrict__ eidx,
                        const float* __restrict__ b1,
                        const float* __restrict__ W2,
                        const float* __restrict__ b2,
                        float* __restrict__ out,
                        int n_edges, int stride_e) {
    __shared__ __align__(16) half_t b1h[128];
    __shared__ __align__(16) half_t w2h[128];
    if (threadIdx.x < 128) {
        const int i = threadIdx.x;
        const int n = (i & 7) * 16 + (i >> 3);   // match Y's column permute
        b1h[i] = (half_t)b1[n];
        w2h[i] = (half_t)W2[n];
    }
    __syncthreads();

    const int lane  = threadIdx.x & 63;
    const int sl    = lane & 15;    // 16-B slice within the 256-B half-row
    const int eslot = lane >> 4;    // which of the wave's 4 edges
    const f16x8 bv = reinterpret_cast<const f16x8*>(b1h)[sl];
    const f16x8 wv = reinterpret_cast<const f16x8*>(w2h)[sl];
    const float b2v = b2[0];
    const f16x2 zero2 = {(_Float16)0, (_Float16)0};

    const int w = blockIdx.x * 4 + (threadIdx.x >> 6);
    int e0 = w * 4;
    if (e0 >= n_edges) return;

    // iter-0 gathers
    int ec = e0 + eslot; if (ec >= n_edges) ec = 0;
    int sa = eidx[ec], da = eidx[n_edges + ec];
    f16x8 u0 = *reinterpret_cast<const f16x8*>(Y + (size_t)sa * 256 + sl * 8);
    f16x8 v0 = *reinterpret_cast<const f16x8*>(Y + (size_t)da * 256 + 128 +
                                               sl * 8);
    // iter-1 gathers
    ec = e0 + stride_e + eslot; if (ec >= n_edges) ec = 0;
    sa = eidx[ec]; da = eidx[n_edges + ec];
    f16x8 u1 = *reinterpret_cast<const f16x8*>(Y + (size_t)sa * 256 + sl * 8);
    f16x8 v1 = *reinterpret_cast<const f16x8*>(Y + (size_t)da * 256 + 128 +
                                               sl * 8);
    // iter-2 indices
    ec = e0 + 2 * stride_e + eslot; if (ec >= n_edges) ec = 0;
    int s2 = eidx[ec], d2 = eidx[n_edges + ec];

    for (; e0 < n_edges; e0 += stride_e) {
        const int e = e0 + eslot;
        const bool valid = (e < n_edges);

        // issue iter+2 gathers (consumed two iterations from now)
        const f16x8 u2 = *reinterpret_cast<const f16x8*>(
            Y + (size_t)s2 * 256 + sl * 8);
        const f16x8 v2 = *reinterpret_cast<const f16x8*>(
            Y + (size_t)d2 * 256 + 128 + sl * 8);

        // fetch indices three iterations ahead
        {
            int en = e0 + 3 * stride_e + eslot;
            if (en >= n_edges) en = 0;
            s2 = eidx[en];
            d2 = eidx[n_edges + en];
        }

        float acc = 0.f;
#pragma unroll
        for (int p = 0; p < 4; ++p) {
            f16x2 h2 = pair2(u0, p) + pair2(v0, p) + pair2(bv, p);
            h2 = __builtin_elementwise_max(h2, zero2);
            acc = __builtin_amdgcn_fdot2(h2, pair2(wv, p), acc, false);
        }
        acc += __shfl_xor(acc, 1);
        acc += __shfl_xor(acc, 2);
        acc += __shfl_xor(acc, 4);
        acc += __shfl_xor(acc, 8);
        if (sl == 0 && valid) out[e] = acc + b2v;

        u0 = u1; v0 = v1;
        u1 = u2; v1 = v2;
    }
}

// Insurance fallback (only if workspace is unexpectedly tiny): correct, slow.
__global__ void naive_edge_kernel(const float* __restrict__ z,
                                  const int* __restrict__ eidx,
                                  const float* __restrict__ W1,
                                  const float* __restrict__ b1,
                                  const float* __restrict__ W2,
                                  const float* __restrict__ b2,
                                  float* __restrict__ out, int n_edges) {
    __shared__ float feat[256];
    __shared__ float red[2];
    const int e = blockIdx.x;
    const int t = threadIdx.x;           // 128 threads
    const int s = eidx[e], d = eidx[n_edges + e];
    feat[t] = z[(size_t)s * 128 + t];
    feat[128 + t] = z[(size_t)d * 128 + t];
    __syncthreads();
    float h = b1[t];
    for (int k = 0; k < 256; ++k) h = fmaf(feat[k], W1[k * 128 + t], h);
    float p = fmaxf(h, 0.f) * W2[t];
    for (int off = 32; off; off >>= 1) p += __shfl_down(p, off);
    if ((t & 63) == 0) red[t >> 6] = p;
    __syncthreads();
    if (t == 0) out[e] = red[0] + red[1] + b2[0];
}

extern "C" void kernel_launch(void* const* d_in, const int* in_sizes, int n_in,
                              void* d_out, int out_size, void* d_ws,
                              size_t ws_size, hipStream_t stream) {
    const float* z   = (const float*)d_in[0];
    const int* eidx  = (const int*)d_in[1];   // int64 ref passed as int32
    const float* W1  = (const float*)d_in[2];
    const float* b1  = (const float*)d_in[3];
    const float* W2  = (const float*)d_in[4];
    const float* b2  = (const float*)d_in[5];
    float* out       = (float*)d_out;

    const int nz      = in_sizes[0];          // 12,800,000
    const int n_nodes = nz / 128;             // 100,000
    const int n_edges = in_sizes[1] / 2;      // 1,000,000

    const size_t Y_bytes   = (size_t)n_nodes * 256 * sizeof(half_t); // 51.2 MB
    const size_t zh_bytes  = (size_t)nz * sizeof(half_t);            // 25.6 MB
    const size_t w1s_bytes = 32768 * sizeof(half_t);                 // 64 KB

    if (ws_size >= Y_bytes + zh_bytes + w1s_bytes) {
        half_t* Y   = (half_t*)d_ws;
        half_t* zh  = (half_t*)((char*)d_ws + Y_bytes);
        half_t* w1s = (half_t*)((char*)d_ws + Y_bytes + zh_bytes);

        const int n8 = nz / 8;                      // 1.6M f16x8 chunks
        const int zblocks = (n8 + 255) / 256;       // 6250
        prep_kernel<<<128 + zblocks, 256, 0, stream>>>(z, W1, zh, w1s, n8);

        const int n_groups = n_nodes / 16;          // 6250 exact
        const int gblocks  = 512;                   // 2 blocks/CU residency
        gemm_uv_kernel<<<gblocks, 256, 0, stream>>>(zh, w1s, Y, n_groups,
                                                    gblocks * 4);

        const int eblocks = 2048;                   // 8 blocks/CU -> 32 w/CU
        edge_decode_kernel<<<eblocks, 256, 0, stream>>>(
            Y, eidx, b1, W2, b2, out, n_edges, eblocks * 4 * 4);
    } else {
        naive_edge_kernel<<<n_edges, 128, 0, stream>>>(z, eidx, W1, b1, W2, b2,
                                                       out, n_edges);
    }
}